// Round 15
// baseline (74.354 us; speedup 1.0000x reference)
//
#include <hip/hip_runtime.h>
#include <hip/hip_bf16.h>

typedef __attribute__((ext_vector_type(8))) short s8v;            // 8 x bf16
typedef __attribute__((ext_vector_type(4))) float f4v;            // 4 x f32

__device__ __forceinline__ short f2bf(float f) {
    __hip_bfloat16 h = __float2bfloat16(f);
    union { __hip_bfloat16 h; short s; } u{h};
    return u.s;
}
__device__ __forceinline__ float bf2f(unsigned short v) {
    union { unsigned u; float f; } x; x.u = ((unsigned)v) << 16; return x.f;
}
__device__ __forceinline__ unsigned packbf(float a, float b) {
    return (unsigned)(unsigned short)f2bf(a) | ((unsigned)(unsigned short)f2bf(b) << 16);
}

// ---------------------------------------------------------------------------
// prep: blocks [0,40) pack weights (W2' = g1 o W2) into MFMA fragment order;
// blocks 40/41 compute LN1-folding vectors s2 = colsum(bf16(W2')), bW2 = b1@W2;
// blocks [42,170) zero the winner array (device-side).
// ---------------------------------------------------------------------------
__global__ void prep_kernel(const float* __restrict__ w1c, const float* __restrict__ w2c,
                            const float* __restrict__ g1c, const float* __restrict__ b1c,
                            const float* __restrict__ w1f, const float* __restrict__ w2f,
                            const float* __restrict__ g1f, const float* __restrict__ b1f,
                            short* __restrict__ p1c, short* __restrict__ p2c,
                            short* __restrict__ p1f, short* __restrict__ p2f,
                            float* __restrict__ s2c, float* __restrict__ bwc,
                            float* __restrict__ s2f, float* __restrict__ bwf,
                            int* __restrict__ win)
{
    int b = blockIdx.x, t = threadIdx.x;
    if (b >= 42) {                        // zero winner: 128 blocks x 256 thr x int4
        int idx4 = (b - 42) * 256 + t;
        int4 z; z.x = 0; z.y = 0; z.z = 0; z.w = 0;
        *(int4*)(win + idx4 * 4) = z;
        return;
    }
    if (b >= 40) {                        // folding vectors
        if (t >= 128) return;
        const float* W  = (b == 40) ? w2c : w2f;
        const float* g1 = (b == 40) ? g1c : g1f;
        const float* b1 = (b == 40) ? b1c : b1f;
        float* s2 = (b == 40) ? s2c : s2f;
        float* bw = (b == 40) ? bwc : bwf;
        float s = 0.f, w2sum = 0.f;
        for (int k = 0; k < 128; ++k) {
            float wv = W[k * 128 + t];
            s     += bf2f((unsigned short)f2bf(g1[k] * wv));  // match MFMA rounding
            w2sum += b1[k] * wv;
        }
        s2[t] = s; bw[t] = w2sum;
        return;
    }
    int id = b * 256 + t;                 // 40*256 = 160 frags * 64 lanes
    int f  = id >> 6, l = id & 63;
    const float* W; const float* g1 = nullptr; short* P; int fl;
    if      (f < 64)  { W = w1c; P = p1c; fl = f; }                   // K=256
    else if (f < 96)  { W = w2c; P = p2c; fl = f - 64;  g1 = g1c; }   // scaled
    else if (f < 128) { W = w1f; P = p1f; fl = f - 96; }
    else              { W = w2f; P = p2f; fl = f - 128; g1 = g1f; }   // scaled
    int g = l >> 4, c = l & 15;
    int ks = fl >> 3, n = fl & 7;
    s8v o;
    #pragma unroll
    for (int e = 0; e < 8; ++e) {
        int k = ks*32 + g*8 + e;
        float v = W[k * 128 + n*16 + c];
        if (g1) v *= g1[k];
        o[e] = f2bf(v);
    }
    *(s8v*)(P + ((fl*64 + l) << 3)) = o;
}

// ---------------------------------------------------------------------------
// Mega-dispatch: [0,512) winner atomicMax | [512,768) coarse MLP (R12 core)
// | [768,1792) xcvt: stream-convert fine X f32 -> bf16 into ws (overlaps
// coarse compute; removes 67MB f32 read + all cvt VALU from the fine kernel).
// ---------------------------------------------------------------------------
__global__ __launch_bounds__(512, 4)
void coarse_mega(const float* __restrict__ X,
                 const short* __restrict__ WpA, const short* __restrict__ WpB,
                 const float* __restrict__ s2v, const float* __restrict__ bwv,
                 const float* __restrict__ g2v, const float* __restrict__ b2v,
                 unsigned short* __restrict__ outB,
                 const int* __restrict__ nr, const int* __restrict__ nc,
                 int* __restrict__ win,
                 const float* __restrict__ Xf, unsigned short* __restrict__ Xbf)
{
    __shared__ short Ws[32768];                // 64 KB

    if (blockIdx.x < 512) {                    // winner: 512*512 = 262144
        int i = blockIdx.x * 512 + threadIdx.x;
        atomicMax(&win[nr[i] * 32 + nc[i]], i + 1);
        return;
    }
    if (blockIdx.x >= 768) {                   // xcvt: 1024 blocks
        int b = blockIdx.x - 768;
        int t = threadIdx.x;
        #pragma unroll
        for (int it = 0; it < 8; ++it) {
            int idx4 = b*4096 + it*512 + t;    // float4 units; 1024*4096 = 4.19M ✔
            float4 v = *(const float4*)(Xf + (size_t)idx4 * 4);
            uint2 p; p.x = packbf(v.x, v.y); p.y = packbf(v.z, v.w);
            *(uint2*)(Xbf + (size_t)idx4 * 4) = p;
        }
        return;
    }
    const int bid  = blockIdx.x - 512;
    const int tid  = threadIdx.x;
    const int lane = tid & 63;
    const int wave = tid >> 6;
    const int G = lane >> 4, n16 = lane & 15;
    const int row = bid * 128 + wave * 16 + n16;
    const size_t rowK = (size_t)row * 256;

    #pragma unroll
    for (int r = 0; r < 8; ++r) {              // W1: 64KB
        int ch = r*512 + tid;
        *(s8v*)&Ws[ch*8] = *(const s8v*)(WpA + (size_t)ch*8);
    }

    const float* pX = X + rowK + G*8;
    float4 aPf[4][2];
    #pragma unroll
    for (int k2 = 0; k2 < 4; ++k2) {
        aPf[k2][0] = *(const float4*)(pX + k2*32);
        aPf[k2][1] = *(const float4*)(pX + k2*32 + 4);
    }
    __syncthreads();

    f4v acc1[8];
    #pragma unroll
    for (int mt = 0; mt < 8; ++mt) acc1[mt] = (f4v){0.f, 0.f, 0.f, 0.f};

    #pragma unroll
    for (int kb = 0; kb < 8; kb += 4) {
        #pragma unroll
        for (int k2 = 0; k2 < 4; ++k2) {
            const int ks = kb + k2;
            s8v wfr[8];
            #pragma unroll
            for (int mt = 0; mt < 8; ++mt)
                wfr[mt] = *(const s8v*)&Ws[((ks*8 + mt)*64 + lane) * 8];
            s8v xf;
            xf[0] = f2bf(aPf[k2][0].x); xf[1] = f2bf(aPf[k2][0].y);
            xf[2] = f2bf(aPf[k2][0].z); xf[3] = f2bf(aPf[k2][0].w);
            xf[4] = f2bf(aPf[k2][1].x); xf[5] = f2bf(aPf[k2][1].y);
            xf[6] = f2bf(aPf[k2][1].z); xf[7] = f2bf(aPf[k2][1].w);
            #pragma unroll
            for (int mt = 0; mt < 8; ++mt)
                acc1[mt] = __builtin_amdgcn_mfma_f32_16x16x32_bf16(wfr[mt], xf, acc1[mt], 0, 0, 0);
        }
        if (kb + 4 < 8) {
            #pragma unroll
            for (int k2 = 0; k2 < 4; ++k2) {
                aPf[k2][0] = *(const float4*)(pX + (kb+4+k2)*32);
                aPf[k2][1] = *(const float4*)(pX + (kb+4+k2)*32 + 4);
            }
        }
    }

    __syncthreads();
    #pragma unroll
    for (int r = 0; r < 4; ++r) {              // re-stage W2' (32KB)
        int ch = r*512 + tid;
        *(s8v*)&Ws[ch*8] = *(const s8v*)(WpB + (size_t)ch*8);
    }
    __syncthreads();

    float sm = 0.f, sq = 0.f;
    #pragma unroll
    for (int mt = 0; mt < 8; ++mt)
        #pragma unroll
        for (int j = 0; j < 4; ++j) { float v = acc1[mt][j]; sm += v; sq += v*v; }
    sm += __shfl_xor(sm, 16, 64); sm += __shfl_xor(sm, 32, 64);
    sq += __shfl_xor(sq, 16, 64); sq += __shfl_xor(sq, 32, 64);
    const float mean1 = sm * (1.f/128.f);
    const float rstd1 = rsqrtf(sq * (1.f/128.f) - mean1*mean1 + 1e-5f);

    unsigned pk[8][2];
    #pragma unroll
    for (int mt = 0; mt < 8; ++mt) {
        pk[mt][0] = packbf(acc1[mt][0], acc1[mt][1]);
        pk[mt][1] = packbf(acc1[mt][2], acc1[mt][3]);
    }

    f4v acc2[8];
    #pragma unroll
    for (int mt = 0; mt < 8; ++mt) acc2[mt] = (f4v){0.f, 0.f, 0.f, 0.f};

    const int src0 = ((G & 1) << 5) + n16;
    const int src1 = src0 + 16;
    const bool hiG = (G >= 2);
    #pragma unroll
    for (int ks = 0; ks < 4; ++ks) {
        int r00 = __shfl((int)pk[2*ks][0],   src0, 64);
        int r01 = __shfl((int)pk[2*ks][1],   src0, 64);
        int r02 = __shfl((int)pk[2*ks][0],   src1, 64);
        int r03 = __shfl((int)pk[2*ks][1],   src1, 64);
        int r10 = __shfl((int)pk[2*ks+1][0], src0, 64);
        int r11 = __shfl((int)pk[2*ks+1][1], src0, 64);
        int r12 = __shfl((int)pk[2*ks+1][0], src1, 64);
        int r13 = __shfl((int)pk[2*ks+1][1], src1, 64);
        union { int u[4]; s8v v; } hb;
        hb.u[0] = hiG ? r10 : r00; hb.u[1] = hiG ? r11 : r01;
        hb.u[2] = hiG ? r12 : r02; hb.u[3] = hiG ? r13 : r03;
        s8v wfr[8];
        #pragma unroll
        for (int mt = 0; mt < 8; ++mt)
            wfr[mt] = *(const s8v*)&Ws[((ks*8 + mt)*64 + lane) * 8];
        #pragma unroll
        for (int mt = 0; mt < 8; ++mt)
            acc2[mt] = __builtin_amdgcn_mfma_f32_16x16x32_bf16(wfr[mt], hb.v, acc2[mt], 0, 0, 0);
    }

    float h2[8][4];
    float sm2 = 0.f, sq2 = 0.f;
    #pragma unroll
    for (int mt = 0; mt < 8; ++mt) {
        const int col = mt*16 + G*4;
        f4v s2l = *(const f4v*)&s2v[col];
        f4v bwl = *(const f4v*)&bwv[col];
        #pragma unroll
        for (int j = 0; j < 4; ++j) {
            float v = rstd1 * (acc2[mt][j] - mean1 * s2l[j]) + bwl[j];
            h2[mt][j] = v; sm2 += v; sq2 += v*v;
        }
    }
    sm2 += __shfl_xor(sm2, 16, 64); sm2 += __shfl_xor(sm2, 32, 64);
    sq2 += __shfl_xor(sq2, 16, 64); sq2 += __shfl_xor(sq2, 32, 64);
    const float mean2 = sm2 * (1.f/128.f);
    const float rstd2 = rsqrtf(sq2 * (1.f/128.f) - mean2*mean2 + 1e-5f);

    #pragma unroll
    for (int mt = 0; mt < 8; ++mt) {
        const int col = mt*16 + G*4;
        f4v g2l = *(const f4v*)&g2v[col];
        f4v b2l = *(const f4v*)&b2v[col];
        ushort4 o;
        o.x = (unsigned short)f2bf(fmaxf((h2[mt][0]-mean2)*rstd2*g2l[0] + b2l[0], 0.f));
        o.y = (unsigned short)f2bf(fmaxf((h2[mt][1]-mean2)*rstd2*g2l[1] + b2l[1], 0.f));
        o.z = (unsigned short)f2bf(fmaxf((h2[mt][2]-mean2)*rstd2*g2l[2] + b2l[2], 0.f));
        o.w = (unsigned short)f2bf(fmaxf((h2[mt][3]-mean2)*rstd2*g2l[3] + b2l[3], 0.f));
        *(ushort4*)(outB + (size_t)row * 128 + col) = o;
    }
}

// ---------------------------------------------------------------------------
// FINE kernel (R15): bf16 X input (pre-converted) -> zero conversion VALU,
// direct per-lane fragment loads. LDS: weights 64KB + 16KB epilogue bounce.
// All global loads (weights, X, winner) issued before the single barrier;
// gather issued right after (hides under both GEMM phases).
// ---------------------------------------------------------------------------
__global__ __launch_bounds__(512, 4)
void fine_mlp(const unsigned short* __restrict__ Xbf,
              const short* __restrict__ WpA, const short* __restrict__ WpB,
              const float* __restrict__ s2v, const float* __restrict__ bwv,
              const float* __restrict__ g2v, const float* __restrict__ b2v,
              float* __restrict__ out,
              const int* __restrict__ winner,
              const unsigned short* __restrict__ fcB)
{
    __shared__ short Ws[32768];     // 64KB: W1 @0, W2' @16384
    __shared__ short Xs[8192];      // 16KB epilogue bounce [128 rows][64 bf16]

    const int tid  = threadIdx.x;
    const int wave = tid >> 6, lane = tid & 63;
    const int G = lane >> 4, n16 = lane & 15;
    const int row0 = blockIdx.x * 128;
    const int rloc = wave * 16 + n16;
    const int row  = row0 + rloc;
    char* xs = (char*)Xs;

    // ---- issue everything: weights -> X fragments -> winner ----
    #pragma unroll
    for (int r = 0; r < 8; ++r) {
        int ch = r*512 + tid;
        *(s8v*)&Ws[ch*8] = *(const s8v*)(WpA + (size_t)ch*8);   // covers W1+W2' (64KB linear)
    }
    s8v xf[4];
    {
        const unsigned short* pX = Xbf + (size_t)row * 128 + G*8;
        #pragma unroll
        for (int ks = 0; ks < 4; ++ks)
            xf[ks] = *(const s8v*)(pX + ks*32);
    }
    int wv = winner[row];
    __syncthreads();

    // ---- gather prefetch (epilogue layout), hides under both GEMMs ----
    s8v gv[2][2];
    int wrr[2];
    {
        const int g8 = lane & 7;
        #pragma unroll
        for (int it = 0; it < 2; ++it) {
            int rr = it*8 + (lane >> 3);
            int w  = __shfl(wv, rr, 64);
            wrr[it] = w;
            size_t src = (size_t)((w > 0 ? w - 1 : 0) & 32767) * 128;
            #pragma unroll
            for (int ch = 0; ch < 2; ++ch)
                gv[it][ch] = *(const s8v*)(fcB + src + ch*64 + g8*8);
        }
    }

    // ---- Layer 1: acc = W1^T @ X^T ----
    f4v acc[8];
    #pragma unroll
    for (int mt = 0; mt < 8; ++mt) acc[mt] = (f4v){0.f, 0.f, 0.f, 0.f};

    #pragma unroll
    for (int ks = 0; ks < 4; ++ks) {
        s8v wfr[8];
        #pragma unroll
        for (int mt = 0; mt < 8; ++mt)
            wfr[mt] = *(const s8v*)&Ws[((ks*8 + mt)*64 + lane) * 8];
        #pragma unroll
        for (int mt = 0; mt < 8; ++mt)
            acc[mt] = __builtin_amdgcn_mfma_f32_16x16x32_bf16(wfr[mt], xf[ks], acc[mt], 0, 0, 0);
    }

    // ---- LN1 stats ----
    float sm = 0.f, sq = 0.f;
    #pragma unroll
    for (int mt = 0; mt < 8; ++mt)
        #pragma unroll
        for (int j = 0; j < 4; ++j) { float v = acc[mt][j]; sm += v; sq += v*v; }
    sm += __shfl_xor(sm, 16, 64); sm += __shfl_xor(sm, 32, 64);
    sq += __shfl_xor(sq, 16, 64); sq += __shfl_xor(sq, 32, 64);
    const float mean1 = sm * (1.f/128.f);
    const float rstd1 = rsqrtf(sq * (1.f/128.f) - mean1*mean1 + 1e-5f);

    unsigned pk[8][2];
    #pragma unroll
    for (int mt = 0; mt < 8; ++mt) {
        pk[mt][0] = packbf(acc[mt][0], acc[mt][1]);
        pk[mt][1] = packbf(acc[mt][2], acc[mt][3]);
        acc[mt] = (f4v){0.f, 0.f, 0.f, 0.f};       // reuse for layer 2
    }

    // ---- Layer 2 (B-frags via shuffles) ----
    const int src0 = ((G & 1) << 5) + n16;
    const int src1 = src0 + 16;
    const bool hiG = (G >= 2);
    #pragma unroll
    for (int ks = 0; ks < 4; ++ks) {
        int r00 = __shfl((int)pk[2*ks][0],   src0, 64);
        int r01 = __shfl((int)pk[2*ks][1],   src0, 64);
        int r02 = __shfl((int)pk[2*ks][0],   src1, 64);
        int r03 = __shfl((int)pk[2*ks][1],   src1, 64);
        int r10 = __shfl((int)pk[2*ks+1][0], src0, 64);
        int r11 = __shfl((int)pk[2*ks+1][1], src0, 64);
        int r12 = __shfl((int)pk[2*ks+1][0], src1, 64);
        int r13 = __shfl((int)pk[2*ks+1][1], src1, 64);
        union { int u[4]; s8v v; } hb;
        hb.u[0] = hiG ? r10 : r00; hb.u[1] = hiG ? r11 : r01;
        hb.u[2] = hiG ? r12 : r02; hb.u[3] = hiG ? r13 : r03;
        s8v wfr[8];
        #pragma unroll
        for (int mt = 0; mt < 8; ++mt)
            wfr[mt] = *(const s8v*)&Ws[16384 + ((ks*8 + mt)*64 + lane) * 8];
        #pragma unroll
        for (int mt = 0; mt < 8; ++mt)
            acc[mt] = __builtin_amdgcn_mfma_f32_16x16x32_bf16(wfr[mt], hb.v, acc[mt], 0, 0, 0);
    }

    // ---- folded LN1 apply + LN2 stats ----
    float h2[8][4];
    float sm2 = 0.f, sq2 = 0.f;
    #pragma unroll
    for (int mt = 0; mt < 8; ++mt) {
        const int col = mt*16 + G*4;
        f4v s2l = *(const f4v*)&s2v[col];
        f4v bwl = *(const f4v*)&bwv[col];
        #pragma unroll
        for (int j = 0; j < 4; ++j) {
            float v = rstd1 * (acc[mt][j] - mean1 * s2l[j]) + bwl[j];
            h2[mt][j] = v; sm2 += v; sq2 += v*v;
        }
    }
    sm2 += __shfl_xor(sm2, 16, 64); sm2 += __shfl_xor(sm2, 32, 64);
    sq2 += __shfl_xor(sq2, 16, 64); sq2 += __shfl_xor(sq2, 32, 64);
    const float mean2 = sm2 * (1.f/128.f);
    const float rstd2 = rsqrtf(sq2 * (1.f/128.f) - mean2*mean2 + 1e-5f);

    // ---- epilogue: per col-half, bounce via Xs then coalesced gather+store ----
    #pragma unroll
    for (int ch = 0; ch < 2; ++ch) {
        #pragma unroll
        for (int mtL = 0; mtL < 4; ++mtL) {
            const int mt = ch*4 + mtL;
            const int col = mt*16 + G*4;
            f4v g2l = *(const f4v*)&g2v[col];
            f4v b2l = *(const f4v*)&b2v[col];
            float z0 = fmaxf((h2[mt][0]-mean2)*rstd2*g2l[0] + b2l[0], 0.f);
            float z1 = fmaxf((h2[mt][1]-mean2)*rstd2*g2l[1] + b2l[1], 0.f);
            float z2 = fmaxf((h2[mt][2]-mean2)*rstd2*g2l[2] + b2l[2], 0.f);
            float z3 = fmaxf((h2[mt][3]-mean2)*rstd2*g2l[3] + b2l[3], 0.f);
            uint2 p; p.x = packbf(z0, z1); p.y = packbf(z2, z3);
            int pg = (mtL*2 + (G >> 1)) ^ (rloc & 7);
            *(uint2*)(xs + rloc*128 + pg*16 + (G & 1)*8) = p;
        }
        asm volatile("s_waitcnt lgkmcnt(0)" ::: "memory");
        #pragma unroll
        for (int it = 0; it < 2; ++it) {
            const int g8  = lane & 7;
            const int rr  = it*8 + (lane >> 3);
            const int rl2 = wave*16 + rr;
            int pg = g8 ^ (rr & 7);
            s8v v = *(const s8v*)(xs + rl2*128 + pg*16);
            float y[8];
            #pragma unroll
            for (int e = 0; e < 8; ++e) y[e] = bf2f((unsigned short)v[e]);
            if (wrr[it] > 0) {
                #pragma unroll
                for (int e = 0; e < 8; ++e) y[e] += bf2f((unsigned short)gv[it][ch][e]);
            }
            float4 o0 = {y[0], y[1], y[2], y[3]};
            float4 o1 = {y[4], y[5], y[6], y[7]};
            float* op = out + (size_t)(row0 + rl2) * 128 + ch*64 + g8*8;
            *(float4*)op       = o0;
            *(float4*)(op + 4) = o1;
        }
        asm volatile("" ::: "memory");
    }
}

extern "C" void kernel_launch(void* const* d_in, const int* in_sizes, int n_in,
                              void* d_out, int out_size, void* d_ws, size_t ws_size,
                              hipStream_t stream)
{
    const float* fcoarse = (const float*)d_in[0];
    const float* ffine   = (const float*)d_in[1];
    const float* w1c = (const float*)d_in[2];
    const float* g1c = (const float*)d_in[3];
    const float* b1c = (const float*)d_in[4];
    const float* w2c = (const float*)d_in[5];
    const float* g2c = (const float*)d_in[6];
    const float* b2c = (const float*)d_in[7];
    const float* w1f = (const float*)d_in[8];
    const float* g1f = (const float*)d_in[9];
    const float* b1f = (const float*)d_in[10];
    const float* w2f = (const float*)d_in[11];
    const float* g2f = (const float*)d_in[12];
    const float* b2f = (const float*)d_in[13];
    const int* nrow  = (const int*)d_in[14];
    const int* ncol  = (const int*)d_in[15];

    float* out = (float*)d_out;
    const int Mc = 32768, Mf = 131072;

    // ws: fcB 8MB | winner 512KB | packs 160KB | folds 2KB | Xbf 33.5MB
    unsigned short* fcB = (unsigned short*)d_ws;
    char* base = (char*)d_ws;
    int*   winner = (int*)(base + 8u*1024*1024);
    short* p1c = (short*)(base + 8u*1024*1024 + 512u*1024);
    short* p2c = p1c + 256*128;
    short* p1f = p2c + 128*128;
    short* p2f = p1f + 128*128;
    float* s2c = (float*)(p2f + 128*128);
    float* bwc = s2c + 128;
    float* s2f = bwc + 128;
    float* bwf = s2f + 128;
    unsigned short* Xbf = (unsigned short*)(base + 9078784u);   // 33.5MB

    // prep: pack weights + fold vectors + zero winner
    prep_kernel<<<170, 256, 0, stream>>>(w1c, w2c, g1c, b1c, w1f, w2f, g1f, b1f,
                                         p1c, p2c, p1f, p2f, s2c, bwc, s2f, bwf,
                                         winner);

    // winner (512) + coarse (256) + fine-X convert (1024) in one dispatch
    coarse_mega<<<1792, 512, 0, stream>>>(
        fcoarse, p1c, p2c, s2c, bwc, g2c, b2c, fcB,
        nrow, ncol, winner, ffine, Xbf);

    // fine MLP + fused scatter -> out (1024 blocks of 128 rows, bf16 X)
    fine_mlp<<<Mf/128, 512, 0, stream>>>(
        Xbf, p1f, p2f, s2f, bwf, g2f, b2f,
        out, winner, fcB);
}

// Round 16
// 71.197 us; speedup vs baseline: 1.0443x; 1.0443x over previous
//
#include <hip/hip_runtime.h>
#include <hip/hip_bf16.h>

typedef __attribute__((ext_vector_type(8))) short s8v;            // 8 x bf16
typedef __attribute__((ext_vector_type(4))) float f4v;            // 4 x f32

__device__ __forceinline__ short f2bf(float f) {
    __hip_bfloat16 h = __float2bfloat16(f);
    union { __hip_bfloat16 h; short s; } u{h};
    return u.s;
}
__device__ __forceinline__ float bf2f(unsigned short v) {
    union { unsigned u; float f; } x; x.u = ((unsigned)v) << 16; return x.f;
}
__device__ __forceinline__ unsigned packbf(float a, float b) {
    return (unsigned)(unsigned short)f2bf(a) | ((unsigned)(unsigned short)f2bf(b) << 16);
}

// ---------------------------------------------------------------------------
// prep: blocks [0,40) pack weights (W2' = g1 o W2) into MFMA fragment order;
// blocks 40/41 compute LN1-folding vectors s2 = colsum(bf16(W2')), bW2 = b1@W2;
// blocks [42,170) zero the winner array (device-side).
// ---------------------------------------------------------------------------
__global__ void prep_kernel(const float* __restrict__ w1c, const float* __restrict__ w2c,
                            const float* __restrict__ g1c, const float* __restrict__ b1c,
                            const float* __restrict__ w1f, const float* __restrict__ w2f,
                            const float* __restrict__ g1f, const float* __restrict__ b1f,
                            short* __restrict__ p1c, short* __restrict__ p2c,
                            short* __restrict__ p1f, short* __restrict__ p2f,
                            float* __restrict__ s2c, float* __restrict__ bwc,
                            float* __restrict__ s2f, float* __restrict__ bwf,
                            int* __restrict__ win)
{
    int b = blockIdx.x, t = threadIdx.x;
    if (b >= 42) {                        // zero winner: 128 blocks x 256 thr x int4
        int idx4 = (b - 42) * 256 + t;
        int4 z; z.x = 0; z.y = 0; z.z = 0; z.w = 0;
        *(int4*)(win + idx4 * 4) = z;
        return;
    }
    if (b >= 40) {                        // folding vectors
        if (t >= 128) return;
        const float* W  = (b == 40) ? w2c : w2f;
        const float* g1 = (b == 40) ? g1c : g1f;
        const float* b1 = (b == 40) ? b1c : b1f;
        float* s2 = (b == 40) ? s2c : s2f;
        float* bw = (b == 40) ? bwc : bwf;
        float s = 0.f, w2sum = 0.f;
        for (int k = 0; k < 128; ++k) {
            float wv = W[k * 128 + t];
            s     += bf2f((unsigned short)f2bf(g1[k] * wv));  // match MFMA rounding
            w2sum += b1[k] * wv;
        }
        s2[t] = s; bw[t] = w2sum;
        return;
    }
    int id = b * 256 + t;                 // 40*256 = 160 frags * 64 lanes
    int f  = id >> 6, l = id & 63;
    const float* W; const float* g1 = nullptr; short* P; int fl;
    if      (f < 64)  { W = w1c; P = p1c; fl = f; }                   // K=256
    else if (f < 96)  { W = w2c; P = p2c; fl = f - 64;  g1 = g1c; }   // scaled
    else if (f < 128) { W = w1f; P = p1f; fl = f - 96; }
    else              { W = w2f; P = p2f; fl = f - 128; g1 = g1f; }   // scaled
    int g = l >> 4, c = l & 15;
    int ks = fl >> 3, n = fl & 7;
    s8v o;
    #pragma unroll
    for (int e = 0; e < 8; ++e) {
        int k = ks*32 + g*8 + e;
        float v = W[k * 128 + n*16 + c];
        if (g1) v *= g1[k];
        o[e] = f2bf(v);
    }
    *(s8v*)(P + ((fl*64 + l) << 3)) = o;
}

// ---------------------------------------------------------------------------
// Mega-dispatch: [0,256) coarse MLP | [256,1280) xcvt (f32->bf16 stream with
// DEEP load batching: 8x16B in flight per lane -> 128KB/CU outstanding, fixes
// the R15 2TB/s concurrency starvation) | [1280,1792) winner atomicMax.
// Coarse blocks first so compute poles spread across CUs and overlap streams.
// ---------------------------------------------------------------------------
__global__ __launch_bounds__(512, 4)
void coarse_mega(const float* __restrict__ X,
                 const short* __restrict__ WpA, const short* __restrict__ WpB,
                 const float* __restrict__ s2v, const float* __restrict__ bwv,
                 const float* __restrict__ g2v, const float* __restrict__ b2v,
                 unsigned short* __restrict__ outB,
                 const int* __restrict__ nr, const int* __restrict__ nc,
                 int* __restrict__ win,
                 const float* __restrict__ Xf, unsigned short* __restrict__ Xbf)
{
    __shared__ short Ws[32768];                // 64 KB

    if (blockIdx.x >= 1280) {                  // winner: 512 blocks
        int i = (blockIdx.x - 1280) * 512 + threadIdx.x;
        atomicMax(&win[nr[i] * 32 + nc[i]], i + 1);
        return;
    }
    if (blockIdx.x >= 256) {                   // xcvt: 1024 blocks, deep-batched
        int b = blockIdx.x - 256;
        int t = threadIdx.x;
        float4 v[8];
        #pragma unroll
        for (int it = 0; it < 8; ++it)
            v[it] = *(const float4*)(Xf + (size_t)(b*4096 + it*512 + t) * 4);
        #pragma unroll
        for (int it = 0; it < 8; ++it) {
            uint2 p; p.x = packbf(v[it].x, v[it].y); p.y = packbf(v[it].z, v[it].w);
            *(uint2*)(Xbf + (size_t)(b*4096 + it*512 + t) * 4) = p;
        }
        return;
    }
    const int bid  = blockIdx.x;
    const int tid  = threadIdx.x;
    const int lane = tid & 63;
    const int wave = tid >> 6;
    const int G = lane >> 4, n16 = lane & 15;
    const int row = bid * 128 + wave * 16 + n16;
    const size_t rowK = (size_t)row * 256;

    #pragma unroll
    for (int r = 0; r < 8; ++r) {              // W1: 64KB
        int ch = r*512 + tid;
        *(s8v*)&Ws[ch*8] = *(const s8v*)(WpA + (size_t)ch*8);
    }

    const float* pX = X + rowK + G*8;
    float4 aPf[4][2];
    #pragma unroll
    for (int k2 = 0; k2 < 4; ++k2) {
        aPf[k2][0] = *(const float4*)(pX + k2*32);
        aPf[k2][1] = *(const float4*)(pX + k2*32 + 4);
    }
    __syncthreads();

    f4v acc1[8];
    #pragma unroll
    for (int mt = 0; mt < 8; ++mt) acc1[mt] = (f4v){0.f, 0.f, 0.f, 0.f};

    #pragma unroll
    for (int kb = 0; kb < 8; kb += 4) {
        #pragma unroll
        for (int k2 = 0; k2 < 4; ++k2) {
            const int ks = kb + k2;
            s8v wfr[8];
            #pragma unroll
            for (int mt = 0; mt < 8; ++mt)
                wfr[mt] = *(const s8v*)&Ws[((ks*8 + mt)*64 + lane) * 8];
            s8v xf;
            xf[0] = f2bf(aPf[k2][0].x); xf[1] = f2bf(aPf[k2][0].y);
            xf[2] = f2bf(aPf[k2][0].z); xf[3] = f2bf(aPf[k2][0].w);
            xf[4] = f2bf(aPf[k2][1].x); xf[5] = f2bf(aPf[k2][1].y);
            xf[6] = f2bf(aPf[k2][1].z); xf[7] = f2bf(aPf[k2][1].w);
            #pragma unroll
            for (int mt = 0; mt < 8; ++mt)
                acc1[mt] = __builtin_amdgcn_mfma_f32_16x16x32_bf16(wfr[mt], xf, acc1[mt], 0, 0, 0);
        }
        if (kb + 4 < 8) {
            #pragma unroll
            for (int k2 = 0; k2 < 4; ++k2) {
                aPf[k2][0] = *(const float4*)(pX + (kb+4+k2)*32);
                aPf[k2][1] = *(const float4*)(pX + (kb+4+k2)*32 + 4);
            }
        }
    }

    __syncthreads();
    #pragma unroll
    for (int r = 0; r < 4; ++r) {              // re-stage W2' (32KB)
        int ch = r*512 + tid;
        *(s8v*)&Ws[ch*8] = *(const s8v*)(WpB + (size_t)ch*8);
    }
    __syncthreads();

    float sm = 0.f, sq = 0.f;
    #pragma unroll
    for (int mt = 0; mt < 8; ++mt)
        #pragma unroll
        for (int j = 0; j < 4; ++j) { float v = acc1[mt][j]; sm += v; sq += v*v; }
    sm += __shfl_xor(sm, 16, 64); sm += __shfl_xor(sm, 32, 64);
    sq += __shfl_xor(sq, 16, 64); sq += __shfl_xor(sq, 32, 64);
    const float mean1 = sm * (1.f/128.f);
    const float rstd1 = rsqrtf(sq * (1.f/128.f) - mean1*mean1 + 1e-5f);

    unsigned pk[8][2];
    #pragma unroll
    for (int mt = 0; mt < 8; ++mt) {
        pk[mt][0] = packbf(acc1[mt][0], acc1[mt][1]);
        pk[mt][1] = packbf(acc1[mt][2], acc1[mt][3]);
    }

    f4v acc2[8];
    #pragma unroll
    for (int mt = 0; mt < 8; ++mt) acc2[mt] = (f4v){0.f, 0.f, 0.f, 0.f};

    const int src0 = ((G & 1) << 5) + n16;
    const int src1 = src0 + 16;
    const bool hiG = (G >= 2);
    #pragma unroll
    for (int ks = 0; ks < 4; ++ks) {
        int r00 = __shfl((int)pk[2*ks][0],   src0, 64);
        int r01 = __shfl((int)pk[2*ks][1],   src0, 64);
        int r02 = __shfl((int)pk[2*ks][0],   src1, 64);
        int r03 = __shfl((int)pk[2*ks][1],   src1, 64);
        int r10 = __shfl((int)pk[2*ks+1][0], src0, 64);
        int r11 = __shfl((int)pk[2*ks+1][1], src0, 64);
        int r12 = __shfl((int)pk[2*ks+1][0], src1, 64);
        int r13 = __shfl((int)pk[2*ks+1][1], src1, 64);
        union { int u[4]; s8v v; } hb;
        hb.u[0] = hiG ? r10 : r00; hb.u[1] = hiG ? r11 : r01;
        hb.u[2] = hiG ? r12 : r02; hb.u[3] = hiG ? r13 : r03;
        s8v wfr[8];
        #pragma unroll
        for (int mt = 0; mt < 8; ++mt)
            wfr[mt] = *(const s8v*)&Ws[((ks*8 + mt)*64 + lane) * 8];
        #pragma unroll
        for (int mt = 0; mt < 8; ++mt)
            acc2[mt] = __builtin_amdgcn_mfma_f32_16x16x32_bf16(wfr[mt], hb.v, acc2[mt], 0, 0, 0);
    }

    float h2[8][4];
    float sm2 = 0.f, sq2 = 0.f;
    #pragma unroll
    for (int mt = 0; mt < 8; ++mt) {
        const int col = mt*16 + G*4;
        f4v s2l = *(const f4v*)&s2v[col];
        f4v bwl = *(const f4v*)&bwv[col];
        #pragma unroll
        for (int j = 0; j < 4; ++j) {
            float v = rstd1 * (acc2[mt][j] - mean1 * s2l[j]) + bwl[j];
            h2[mt][j] = v; sm2 += v; sq2 += v*v;
        }
    }
    sm2 += __shfl_xor(sm2, 16, 64); sm2 += __shfl_xor(sm2, 32, 64);
    sq2 += __shfl_xor(sq2, 16, 64); sq2 += __shfl_xor(sq2, 32, 64);
    const float mean2 = sm2 * (1.f/128.f);
    const float rstd2 = rsqrtf(sq2 * (1.f/128.f) - mean2*mean2 + 1e-5f);

    #pragma unroll
    for (int mt = 0; mt < 8; ++mt) {
        const int col = mt*16 + G*4;
        f4v g2l = *(const f4v*)&g2v[col];
        f4v b2l = *(const f4v*)&b2v[col];
        ushort4 o;
        o.x = (unsigned short)f2bf(fmaxf((h2[mt][0]-mean2)*rstd2*g2l[0] + b2l[0], 0.f));
        o.y = (unsigned short)f2bf(fmaxf((h2[mt][1]-mean2)*rstd2*g2l[1] + b2l[1], 0.f));
        o.z = (unsigned short)f2bf(fmaxf((h2[mt][2]-mean2)*rstd2*g2l[2] + b2l[2], 0.f));
        o.w = (unsigned short)f2bf(fmaxf((h2[mt][3]-mean2)*rstd2*g2l[3] + b2l[3], 0.f));
        *(ushort4*)(outB + (size_t)row * 128 + col) = o;
    }
}

// ---------------------------------------------------------------------------
// FINE kernel (R15, unchanged - fast): bf16 X input, zero conversion VALU,
// direct per-lane fragment loads; weights LDS-resident; epilogue LDS bounce.
// ---------------------------------------------------------------------------
__global__ __launch_bounds__(512, 4)
void fine_mlp(const unsigned short* __restrict__ Xbf,
              const short* __restrict__ WpA, const short* __restrict__ WpB,
              const float* __restrict__ s2v, const float* __restrict__ bwv,
              const float* __restrict__ g2v, const float* __restrict__ b2v,
              float* __restrict__ out,
              const int* __restrict__ winner,
              const unsigned short* __restrict__ fcB)
{
    __shared__ short Ws[32768];     // 64KB: W1 @0, W2' @16384
    __shared__ short Xs[8192];      // 16KB epilogue bounce [128 rows][64 bf16]

    const int tid  = threadIdx.x;
    const int wave = tid >> 6, lane = tid & 63;
    const int G = lane >> 4, n16 = lane & 15;
    const int row0 = blockIdx.x * 128;
    const int rloc = wave * 16 + n16;
    const int row  = row0 + rloc;
    char* xs = (char*)Xs;

    // ---- issue everything: weights -> X fragments -> winner ----
    #pragma unroll
    for (int r = 0; r < 8; ++r) {
        int ch = r*512 + tid;
        *(s8v*)&Ws[ch*8] = *(const s8v*)(WpA + (size_t)ch*8);   // W1+W2' contiguous
    }
    s8v xf[4];
    {
        const unsigned short* pX = Xbf + (size_t)row * 128 + G*8;
        #pragma unroll
        for (int ks = 0; ks < 4; ++ks)
            xf[ks] = *(const s8v*)(pX + ks*32);
    }
    int wv = winner[row];
    __syncthreads();

    // ---- gather prefetch (epilogue layout), hides under both GEMMs ----
    s8v gv[2][2];
    int wrr[2];
    {
        const int g8 = lane & 7;
        #pragma unroll
        for (int it = 0; it < 2; ++it) {
            int rr = it*8 + (lane >> 3);
            int w  = __shfl(wv, rr, 64);
            wrr[it] = w;
            size_t src = (size_t)((w > 0 ? w - 1 : 0) & 32767) * 128;
            #pragma unroll
            for (int ch = 0; ch < 2; ++ch)
                gv[it][ch] = *(const s8v*)(fcB + src + ch*64 + g8*8);
        }
    }

    // ---- Layer 1: acc = W1^T @ X^T ----
    f4v acc[8];
    #pragma unroll
    for (int mt = 0; mt < 8; ++mt) acc[mt] = (f4v){0.f, 0.f, 0.f, 0.f};

    #pragma unroll
    for (int ks = 0; ks < 4; ++ks) {
        s8v wfr[8];
        #pragma unroll
        for (int mt = 0; mt < 8; ++mt)
            wfr[mt] = *(const s8v*)&Ws[((ks*8 + mt)*64 + lane) * 8];
        #pragma unroll
        for (int mt = 0; mt < 8; ++mt)
            acc[mt] = __builtin_amdgcn_mfma_f32_16x16x32_bf16(wfr[mt], xf[ks], acc[mt], 0, 0, 0);
    }

    // ---- LN1 stats ----
    float sm = 0.f, sq = 0.f;
    #pragma unroll
    for (int mt = 0; mt < 8; ++mt)
        #pragma unroll
        for (int j = 0; j < 4; ++j) { float v = acc[mt][j]; sm += v; sq += v*v; }
    sm += __shfl_xor(sm, 16, 64); sm += __shfl_xor(sm, 32, 64);
    sq += __shfl_xor(sq, 16, 64); sq += __shfl_xor(sq, 32, 64);
    const float mean1 = sm * (1.f/128.f);
    const float rstd1 = rsqrtf(sq * (1.f/128.f) - mean1*mean1 + 1e-5f);

    unsigned pk[8][2];
    #pragma unroll
    for (int mt = 0; mt < 8; ++mt) {
        pk[mt][0] = packbf(acc[mt][0], acc[mt][1]);
        pk[mt][1] = packbf(acc[mt][2], acc[mt][3]);
        acc[mt] = (f4v){0.f, 0.f, 0.f, 0.f};       // reuse for layer 2
    }

    // ---- Layer 2 (B-frags via shuffles) ----
    const int src0 = ((G & 1) << 5) + n16;
    const int src1 = src0 + 16;
    const bool hiG = (G >= 2);
    #pragma unroll
    for (int ks = 0; ks < 4; ++ks) {
        int r00 = __shfl((int)pk[2*ks][0],   src0, 64);
        int r01 = __shfl((int)pk[2*ks][1],   src0, 64);
        int r02 = __shfl((int)pk[2*ks][0],   src1, 64);
        int r03 = __shfl((int)pk[2*ks][1],   src1, 64);
        int r10 = __shfl((int)pk[2*ks+1][0], src0, 64);
        int r11 = __shfl((int)pk[2*ks+1][1], src0, 64);
        int r12 = __shfl((int)pk[2*ks+1][0], src1, 64);
        int r13 = __shfl((int)pk[2*ks+1][1], src1, 64);
        union { int u[4]; s8v v; } hb;
        hb.u[0] = hiG ? r10 : r00; hb.u[1] = hiG ? r11 : r01;
        hb.u[2] = hiG ? r12 : r02; hb.u[3] = hiG ? r13 : r03;
        s8v wfr[8];
        #pragma unroll
        for (int mt = 0; mt < 8; ++mt)
            wfr[mt] = *(const s8v*)&Ws[16384 + ((ks*8 + mt)*64 + lane) * 8];
        #pragma unroll
        for (int mt = 0; mt < 8; ++mt)
            acc[mt] = __builtin_amdgcn_mfma_f32_16x16x32_bf16(wfr[mt], hb.v, acc[mt], 0, 0, 0);
    }

    // ---- folded LN1 apply + LN2 stats ----
    float h2[8][4];
    float sm2 = 0.f, sq2 = 0.f;
    #pragma unroll
    for (int mt = 0; mt < 8; ++mt) {
        const int col = mt*16 + G*4;
        f4v s2l = *(const f4v*)&s2v[col];
        f4v bwl = *(const f4v*)&bwv[col];
        #pragma unroll
        for (int j = 0; j < 4; ++j) {
            float v = rstd1 * (acc[mt][j] - mean1 * s2l[j]) + bwl[j];
            h2[mt][j] = v; sm2 += v; sq2 += v*v;
        }
    }
    sm2 += __shfl_xor(sm2, 16, 64); sm2 += __shfl_xor(sm2, 32, 64);
    sq2 += __shfl_xor(sq2, 16, 64); sq2 += __shfl_xor(sq2, 32, 64);
    const float mean2 = sm2 * (1.f/128.f);
    const float rstd2 = rsqrtf(sq2 * (1.f/128.f) - mean2*mean2 + 1e-5f);

    // ---- epilogue: per col-half, bounce via Xs then coalesced gather+store ----
    #pragma unroll
    for (int ch = 0; ch < 2; ++ch) {
        #pragma unroll
        for (int mtL = 0; mtL < 4; ++mtL) {
            const int mt = ch*4 + mtL;
            const int col = mt*16 + G*4;
            f4v g2l = *(const f4v*)&g2v[col];
            f4v b2l = *(const f4v*)&b2v[col];
            float z0 = fmaxf((h2[mt][0]-mean2)*rstd2*g2l[0] + b2l[0], 0.f);
            float z1 = fmaxf((h2[mt][1]-mean2)*rstd2*g2l[1] + b2l[1], 0.f);
            float z2 = fmaxf((h2[mt][2]-mean2)*rstd2*g2l[2] + b2l[2], 0.f);
            float z3 = fmaxf((h2[mt][3]-mean2)*rstd2*g2l[3] + b2l[3], 0.f);
            uint2 p; p.x = packbf(z0, z1); p.y = packbf(z2, z3);
            int pg = (mtL*2 + (G >> 1)) ^ (rloc & 7);
            *(uint2*)(xs + rloc*128 + pg*16 + (G & 1)*8) = p;
        }
        asm volatile("s_waitcnt lgkmcnt(0)" ::: "memory");
        #pragma unroll
        for (int it = 0; it < 2; ++it) {
            const int g8  = lane & 7;
            const int rr  = it*8 + (lane >> 3);
            const int rl2 = wave*16 + rr;
            int pg = g8 ^ (rr & 7);
            s8v v = *(const s8v*)(xs + rl2*128 + pg*16);
            float y[8];
            #pragma unroll
            for (int e = 0; e < 8; ++e) y[e] = bf2f((unsigned short)v[e]);
            if (wrr[it] > 0) {
                #pragma unroll
                for (int e = 0; e < 8; ++e) y[e] += bf2f((unsigned short)gv[it][ch][e]);
            }
            float4 o0 = {y[0], y[1], y[2], y[3]};
            float4 o1 = {y[4], y[5], y[6], y[7]};
            float* op = out + (size_t)(row0 + rl2) * 128 + ch*64 + g8*8;
            *(float4*)op       = o0;
            *(float4*)(op + 4) = o1;
        }
        asm volatile("" ::: "memory");
    }
}

extern "C" void kernel_launch(void* const* d_in, const int* in_sizes, int n_in,
                              void* d_out, int out_size, void* d_ws, size_t ws_size,
                              hipStream_t stream)
{
    const float* fcoarse = (const float*)d_in[0];
    const float* ffine   = (const float*)d_in[1];
    const float* w1c = (const float*)d_in[2];
    const float* g1c = (const float*)d_in[3];
    const float* b1c = (const float*)d_in[4];
    const float* w2c = (const float*)d_in[5];
    const float* g2c = (const float*)d_in[6];
    const float* b2c = (const float*)d_in[7];
    const float* w1f = (const float*)d_in[8];
    const float* g1f = (const float*)d_in[9];
    const float* b1f = (const float*)d_in[10];
    const float* w2f = (const float*)d_in[11];
    const float* g2f = (const float*)d_in[12];
    const float* b2f = (const float*)d_in[13];
    const int* nrow  = (const int*)d_in[14];
    const int* ncol  = (const int*)d_in[15];

    float* out = (float*)d_out;
    const int Mc = 32768, Mf = 131072;

    // ws: fcB 8MB | winner 512KB | packs 160KB | folds 2KB | Xbf 33.5MB
    unsigned short* fcB = (unsigned short*)d_ws;
    char* base = (char*)d_ws;
    int*   winner = (int*)(base + 8u*1024*1024);
    short* p1c = (short*)(base + 8u*1024*1024 + 512u*1024);
    short* p2c = p1c + 256*128;
    short* p1f = p2c + 128*128;
    short* p2f = p1f + 128*128;
    float* s2c = (float*)(p2f + 128*128);
    float* bwc = s2c + 128;
    float* s2f = bwc + 128;
    float* bwf = s2f + 128;
    unsigned short* Xbf = (unsigned short*)(base + 9078784u);   // 33.5MB

    // prep: pack weights + fold vectors + zero winner
    prep_kernel<<<170, 256, 0, stream>>>(w1c, w2c, g1c, b1c, w1f, w2f, g1f, b1f,
                                         p1c, p2c, p1f, p2f, s2c, bwc, s2f, bwf,
                                         winner);

    // coarse (256) + fine-X convert (1024, deep-batched) + winner (512)
    coarse_mega<<<1792, 512, 0, stream>>>(
        fcoarse, p1c, p2c, s2c, bwc, g2c, b2c, fcB,
        nrow, ncol, winner, ffine, Xbf);

    // fine MLP + fused scatter -> out (1024 blocks of 128 rows, bf16 X)
    fine_mlp<<<Mf/128, 512, 0, stream>>>(
        Xbf, p1f, p2f, s2f, bwf, g2f, b2f,
        out, winner, fcB);
}

// Round 17
// 71.002 us; speedup vs baseline: 1.0472x; 1.0027x over previous
//
#include <hip/hip_runtime.h>
#include <hip/hip_bf16.h>

typedef __attribute__((ext_vector_type(8))) short s8v;            // 8 x bf16
typedef __attribute__((ext_vector_type(4))) float f4v;            // 4 x f32

__device__ __forceinline__ short f2bf(float f) {
    __hip_bfloat16 h = __float2bfloat16(f);
    union { __hip_bfloat16 h; short s; } u{h};
    return u.s;
}
__device__ __forceinline__ float bf2f(unsigned short v) {
    union { unsigned u; float f; } x; x.u = ((unsigned)v) << 16; return x.f;
}
__device__ __forceinline__ unsigned packbf(float a, float b) {
    return (unsigned)(unsigned short)f2bf(a) | ((unsigned)(unsigned short)f2bf(b) << 16);
}

// ---------------------------------------------------------------------------
// prep_mega (NO LDS -> high occupancy for the streaming blocks):
//   [0,40)      pack weights into MFMA fragment order (W2' = g1 o W2)
//   [40,42)     LN1-folding vectors s2 = colsum(bf16(W2')), bW2 = b1@W2
//   [42,170)    zero winner array
//   [170,2218)  xcvt: fine X f32 -> bf16, deep-batched 8x16B per lane
// ---------------------------------------------------------------------------
__global__ void prep_mega(const float* __restrict__ w1c, const float* __restrict__ w2c,
                          const float* __restrict__ g1c, const float* __restrict__ b1c,
                          const float* __restrict__ w1f, const float* __restrict__ w2f,
                          const float* __restrict__ g1f, const float* __restrict__ b1f,
                          short* __restrict__ p1c, short* __restrict__ p2c,
                          short* __restrict__ p1f, short* __restrict__ p2f,
                          float* __restrict__ s2c, float* __restrict__ bwc,
                          float* __restrict__ s2f, float* __restrict__ bwf,
                          int* __restrict__ win,
                          const float* __restrict__ Xf, unsigned short* __restrict__ Xbf)
{
    int b = blockIdx.x, t = threadIdx.x;
    if (b >= 170) {                       // xcvt: 2048 blocks x 256 thr x 8 float4
        const size_t base4 = (size_t)(b - 170) * 2048;
        float4 v[8];
        #pragma unroll
        for (int it = 0; it < 8; ++it)
            v[it] = *(const float4*)(Xf + (base4 + it*256 + t) * 4);
        #pragma unroll
        for (int it = 0; it < 8; ++it) {
            uint2 p; p.x = packbf(v[it].x, v[it].y); p.y = packbf(v[it].z, v[it].w);
            *(uint2*)(Xbf + (base4 + it*256 + t) * 4) = p;
        }
        return;
    }
    if (b >= 42) {                        // zero winner: 128 blocks x 256 thr x int4
        int idx4 = (b - 42) * 256 + t;
        int4 z; z.x = 0; z.y = 0; z.z = 0; z.w = 0;
        *(int4*)(win + idx4 * 4) = z;
        return;
    }
    if (b >= 40) {                        // folding vectors
        if (t >= 128) return;
        const float* W  = (b == 40) ? w2c : w2f;
        const float* g1 = (b == 40) ? g1c : g1f;
        const float* b1 = (b == 40) ? b1c : b1f;
        float* s2 = (b == 40) ? s2c : s2f;
        float* bw = (b == 40) ? bwc : bwf;
        float s = 0.f, w2sum = 0.f;
        for (int k = 0; k < 128; ++k) {
            float wv = W[k * 128 + t];
            s     += bf2f((unsigned short)f2bf(g1[k] * wv));  // match MFMA rounding
            w2sum += b1[k] * wv;
        }
        s2[t] = s; bw[t] = w2sum;
        return;
    }
    int id = b * 256 + t;                 // 40*256 = 160 frags * 64 lanes
    int f  = id >> 6, l = id & 63;
    const float* W; const float* g1 = nullptr; short* P; int fl;
    if      (f < 64)  { W = w1c; P = p1c; fl = f; }                   // K=256
    else if (f < 96)  { W = w2c; P = p2c; fl = f - 64;  g1 = g1c; }   // scaled
    else if (f < 128) { W = w1f; P = p1f; fl = f - 96; }
    else              { W = w2f; P = p2f; fl = f - 128; g1 = g1f; }   // scaled
    int g = l >> 4, c = l & 15;
    int ks = fl >> 3, n = fl & 7;
    s8v o;
    #pragma unroll
    for (int e = 0; e < 8; ++e) {
        int k = ks*32 + g*8 + e;
        float v = W[k * 128 + n*16 + c];
        if (g1) v *= g1[k];
        o[e] = f2bf(v);
    }
    *(s8v*)(P + ((fl*64 + l) << 3)) = o;
}

// ---------------------------------------------------------------------------
// Dispatch 2: [0,256) coarse MLP (R12 core, proven) | [256,768) winner
// atomicMax (i+1 encoding). Coarse fits one occupancy round (2 blk/CU).
// ---------------------------------------------------------------------------
__global__ __launch_bounds__(512, 4)
void coarse_mega(const float* __restrict__ X,
                 const short* __restrict__ WpA, const short* __restrict__ WpB,
                 const float* __restrict__ s2v, const float* __restrict__ bwv,
                 const float* __restrict__ g2v, const float* __restrict__ b2v,
                 unsigned short* __restrict__ outB,
                 const int* __restrict__ nr, const int* __restrict__ nc,
                 int* __restrict__ win)
{
    __shared__ short Ws[32768];                // 64 KB

    if (blockIdx.x >= 256) {                   // winner: 512 blocks x 512 thr
        int i = (blockIdx.x - 256) * 512 + threadIdx.x;
        atomicMax(&win[nr[i] * 32 + nc[i]], i + 1);
        return;
    }
    const int bid  = blockIdx.x;
    const int tid  = threadIdx.x;
    const int lane = tid & 63;
    const int wave = tid >> 6;
    const int G = lane >> 4, n16 = lane & 15;
    const int row = bid * 128 + wave * 16 + n16;
    const size_t rowK = (size_t)row * 256;

    #pragma unroll
    for (int r = 0; r < 8; ++r) {              // W1: 64KB
        int ch = r*512 + tid;
        *(s8v*)&Ws[ch*8] = *(const s8v*)(WpA + (size_t)ch*8);
    }

    const float* pX = X + rowK + G*8;
    float4 aPf[4][2];
    #pragma unroll
    for (int k2 = 0; k2 < 4; ++k2) {
        aPf[k2][0] = *(const float4*)(pX + k2*32);
        aPf[k2][1] = *(const float4*)(pX + k2*32 + 4);
    }
    __syncthreads();

    f4v acc1[8];
    #pragma unroll
    for (int mt = 0; mt < 8; ++mt) acc1[mt] = (f4v){0.f, 0.f, 0.f, 0.f};

    #pragma unroll
    for (int kb = 0; kb < 8; kb += 4) {
        #pragma unroll
        for (int k2 = 0; k2 < 4; ++k2) {
            const int ks = kb + k2;
            s8v wfr[8];
            #pragma unroll
            for (int mt = 0; mt < 8; ++mt)
                wfr[mt] = *(const s8v*)&Ws[((ks*8 + mt)*64 + lane) * 8];
            s8v xf;
            xf[0] = f2bf(aPf[k2][0].x); xf[1] = f2bf(aPf[k2][0].y);
            xf[2] = f2bf(aPf[k2][0].z); xf[3] = f2bf(aPf[k2][0].w);
            xf[4] = f2bf(aPf[k2][1].x); xf[5] = f2bf(aPf[k2][1].y);
            xf[6] = f2bf(aPf[k2][1].z); xf[7] = f2bf(aPf[k2][1].w);
            #pragma unroll
            for (int mt = 0; mt < 8; ++mt)
                acc1[mt] = __builtin_amdgcn_mfma_f32_16x16x32_bf16(wfr[mt], xf, acc1[mt], 0, 0, 0);
        }
        if (kb + 4 < 8) {
            #pragma unroll
            for (int k2 = 0; k2 < 4; ++k2) {
                aPf[k2][0] = *(const float4*)(pX + (kb+4+k2)*32);
                aPf[k2][1] = *(const float4*)(pX + (kb+4+k2)*32 + 4);
            }
        }
    }

    __syncthreads();
    #pragma unroll
    for (int r = 0; r < 4; ++r) {              // re-stage W2' (32KB)
        int ch = r*512 + tid;
        *(s8v*)&Ws[ch*8] = *(const s8v*)(WpB + (size_t)ch*8);
    }
    __syncthreads();

    float sm = 0.f, sq = 0.f;
    #pragma unroll
    for (int mt = 0; mt < 8; ++mt)
        #pragma unroll
        for (int j = 0; j < 4; ++j) { float v = acc1[mt][j]; sm += v; sq += v*v; }
    sm += __shfl_xor(sm, 16, 64); sm += __shfl_xor(sm, 32, 64);
    sq += __shfl_xor(sq, 16, 64); sq += __shfl_xor(sq, 32, 64);
    const float mean1 = sm * (1.f/128.f);
    const float rstd1 = rsqrtf(sq * (1.f/128.f) - mean1*mean1 + 1e-5f);

    unsigned pk[8][2];
    #pragma unroll
    for (int mt = 0; mt < 8; ++mt) {
        pk[mt][0] = packbf(acc1[mt][0], acc1[mt][1]);
        pk[mt][1] = packbf(acc1[mt][2], acc1[mt][3]);
    }

    f4v acc2[8];
    #pragma unroll
    for (int mt = 0; mt < 8; ++mt) acc2[mt] = (f4v){0.f, 0.f, 0.f, 0.f};

    const int src0 = ((G & 1) << 5) + n16;
    const int src1 = src0 + 16;
    const bool hiG = (G >= 2);
    #pragma unroll
    for (int ks = 0; ks < 4; ++ks) {
        int r00 = __shfl((int)pk[2*ks][0],   src0, 64);
        int r01 = __shfl((int)pk[2*ks][1],   src0, 64);
        int r02 = __shfl((int)pk[2*ks][0],   src1, 64);
        int r03 = __shfl((int)pk[2*ks][1],   src1, 64);
        int r10 = __shfl((int)pk[2*ks+1][0], src0, 64);
        int r11 = __shfl((int)pk[2*ks+1][1], src0, 64);
        int r12 = __shfl((int)pk[2*ks+1][0], src1, 64);
        int r13 = __shfl((int)pk[2*ks+1][1], src1, 64);
        union { int u[4]; s8v v; } hb;
        hb.u[0] = hiG ? r10 : r00; hb.u[1] = hiG ? r11 : r01;
        hb.u[2] = hiG ? r12 : r02; hb.u[3] = hiG ? r13 : r03;
        s8v wfr[8];
        #pragma unroll
        for (int mt = 0; mt < 8; ++mt)
            wfr[mt] = *(const s8v*)&Ws[((ks*8 + mt)*64 + lane) * 8];
        #pragma unroll
        for (int mt = 0; mt < 8; ++mt)
            acc2[mt] = __builtin_amdgcn_mfma_f32_16x16x32_bf16(wfr[mt], hb.v, acc2[mt], 0, 0, 0);
    }

    float h2[8][4];
    float sm2 = 0.f, sq2 = 0.f;
    #pragma unroll
    for (int mt = 0; mt < 8; ++mt) {
        const int col = mt*16 + G*4;
        f4v s2l = *(const f4v*)&s2v[col];
        f4v bwl = *(const f4v*)&bwv[col];
        #pragma unroll
        for (int j = 0; j < 4; ++j) {
            float v = rstd1 * (acc2[mt][j] - mean1 * s2l[j]) + bwl[j];
            h2[mt][j] = v; sm2 += v; sq2 += v*v;
        }
    }
    sm2 += __shfl_xor(sm2, 16, 64); sm2 += __shfl_xor(sm2, 32, 64);
    sq2 += __shfl_xor(sq2, 16, 64); sq2 += __shfl_xor(sq2, 32, 64);
    const float mean2 = sm2 * (1.f/128.f);
    const float rstd2 = rsqrtf(sq2 * (1.f/128.f) - mean2*mean2 + 1e-5f);

    #pragma unroll
    for (int mt = 0; mt < 8; ++mt) {
        const int col = mt*16 + G*4;
        f4v g2l = *(const f4v*)&g2v[col];
        f4v b2l = *(const f4v*)&b2v[col];
        ushort4 o;
        o.x = (unsigned short)f2bf(fmaxf((h2[mt][0]-mean2)*rstd2*g2l[0] + b2l[0], 0.f));
        o.y = (unsigned short)f2bf(fmaxf((h2[mt][1]-mean2)*rstd2*g2l[1] + b2l[1], 0.f));
        o.z = (unsigned short)f2bf(fmaxf((h2[mt][2]-mean2)*rstd2*g2l[2] + b2l[2], 0.f));
        o.w = (unsigned short)f2bf(fmaxf((h2[mt][3]-mean2)*rstd2*g2l[3] + b2l[3], 0.f));
        *(ushort4*)(outB + (size_t)row * 128 + col) = o;
    }
}

// ---------------------------------------------------------------------------
// FINE kernel (R15, unchanged - ~20us, near its traffic roofline): bf16 X,
// zero conversion VALU, weights LDS-resident, epilogue LDS bounce.
// ---------------------------------------------------------------------------
__global__ __launch_bounds__(512, 4)
void fine_mlp(const unsigned short* __restrict__ Xbf,
              const short* __restrict__ WpA, const short* __restrict__ WpB,
              const float* __restrict__ s2v, const float* __restrict__ bwv,
              const float* __restrict__ g2v, const float* __restrict__ b2v,
              float* __restrict__ out,
              const int* __restrict__ winner,
              const unsigned short* __restrict__ fcB)
{
    __shared__ short Ws[32768];     // 64KB: W1 @0, W2' @16384
    __shared__ short Xs[8192];      // 16KB epilogue bounce [128 rows][64 bf16]

    const int tid  = threadIdx.x;
    const int wave = tid >> 6, lane = tid & 63;
    const int G = lane >> 4, n16 = lane & 15;
    const int row0 = blockIdx.x * 128;
    const int rloc = wave * 16 + n16;
    const int row  = row0 + rloc;
    char* xs = (char*)Xs;

    // ---- issue everything: weights -> X fragments -> winner ----
    #pragma unroll
    for (int r = 0; r < 8; ++r) {
        int ch = r*512 + tid;
        *(s8v*)&Ws[ch*8] = *(const s8v*)(WpA + (size_t)ch*8);   // W1+W2' contiguous
    }
    s8v xf[4];
    {
        const unsigned short* pX = Xbf + (size_t)row * 128 + G*8;
        #pragma unroll
        for (int ks = 0; ks < 4; ++ks)
            xf[ks] = *(const s8v*)(pX + ks*32);
    }
    int wv = winner[row];
    __syncthreads();

    // ---- gather prefetch (epilogue layout), hides under both GEMMs ----
    s8v gv[2][2];
    int wrr[2];
    {
        const int g8 = lane & 7;
        #pragma unroll
        for (int it = 0; it < 2; ++it) {
            int rr = it*8 + (lane >> 3);
            int w  = __shfl(wv, rr, 64);
            wrr[it] = w;
            size_t src = (size_t)((w > 0 ? w - 1 : 0) & 32767) * 128;
            #pragma unroll
            for (int ch = 0; ch < 2; ++ch)
                gv[it][ch] = *(const s8v*)(fcB + src + ch*64 + g8*8);
        }
    }

    // ---- Layer 1: acc = W1^T @ X^T ----
    f4v acc[8];
    #pragma unroll
    for (int mt = 0; mt < 8; ++mt) acc[mt] = (f4v){0.f, 0.f, 0.f, 0.f};

    #pragma unroll
    for (int ks = 0; ks < 4; ++ks) {
        s8v wfr[8];
        #pragma unroll
        for (int mt = 0; mt < 8; ++mt)
            wfr[mt] = *(const s8v*)&Ws[((ks*8 + mt)*64 + lane) * 8];
        #pragma unroll
        for (int mt = 0; mt < 8; ++mt)
            acc[mt] = __builtin_amdgcn_mfma_f32_16x16x32_bf16(wfr[mt], xf[ks], acc[mt], 0, 0, 0);
    }

    // ---- LN1 stats ----
    float sm = 0.f, sq = 0.f;
    #pragma unroll
    for (int mt = 0; mt < 8; ++mt)
        #pragma unroll
        for (int j = 0; j < 4; ++j) { float v = acc[mt][j]; sm += v; sq += v*v; }
    sm += __shfl_xor(sm, 16, 64); sm += __shfl_xor(sm, 32, 64);
    sq += __shfl_xor(sq, 16, 64); sq += __shfl_xor(sq, 32, 64);
    const float mean1 = sm * (1.f/128.f);
    const float rstd1 = rsqrtf(sq * (1.f/128.f) - mean1*mean1 + 1e-5f);

    unsigned pk[8][2];
    #pragma unroll
    for (int mt = 0; mt < 8; ++mt) {
        pk[mt][0] = packbf(acc[mt][0], acc[mt][1]);
        pk[mt][1] = packbf(acc[mt][2], acc[mt][3]);
        acc[mt] = (f4v){0.f, 0.f, 0.f, 0.f};       // reuse for layer 2
    }

    // ---- Layer 2 (B-frags via shuffles) ----
    const int src0 = ((G & 1) << 5) + n16;
    const int src1 = src0 + 16;
    const bool hiG = (G >= 2);
    #pragma unroll
    for (int ks = 0; ks < 4; ++ks) {
        int r00 = __shfl((int)pk[2*ks][0],   src0, 64);
        int r01 = __shfl((int)pk[2*ks][1],   src0, 64);
        int r02 = __shfl((int)pk[2*ks][0],   src1, 64);
        int r03 = __shfl((int)pk[2*ks][1],   src1, 64);
        int r10 = __shfl((int)pk[2*ks+1][0], src0, 64);
        int r11 = __shfl((int)pk[2*ks+1][1], src0, 64);
        int r12 = __shfl((int)pk[2*ks+1][0], src1, 64);
        int r13 = __shfl((int)pk[2*ks+1][1], src1, 64);
        union { int u[4]; s8v v; } hb;
        hb.u[0] = hiG ? r10 : r00; hb.u[1] = hiG ? r11 : r01;
        hb.u[2] = hiG ? r12 : r02; hb.u[3] = hiG ? r13 : r03;
        s8v wfr[8];
        #pragma unroll
        for (int mt = 0; mt < 8; ++mt)
            wfr[mt] = *(const s8v*)&Ws[16384 + ((ks*8 + mt)*64 + lane) * 8];
        #pragma unroll
        for (int mt = 0; mt < 8; ++mt)
            acc[mt] = __builtin_amdgcn_mfma_f32_16x16x32_bf16(wfr[mt], hb.v, acc[mt], 0, 0, 0);
    }

    // ---- folded LN1 apply + LN2 stats ----
    float h2[8][4];
    float sm2 = 0.f, sq2 = 0.f;
    #pragma unroll
    for (int mt = 0; mt < 8; ++mt) {
        const int col = mt*16 + G*4;
        f4v s2l = *(const f4v*)&s2v[col];
        f4v bwl = *(const f4v*)&bwv[col];
        #pragma unroll
        for (int j = 0; j < 4; ++j) {
            float v = rstd1 * (acc[mt][j] - mean1 * s2l[j]) + bwl[j];
            h2[mt][j] = v; sm2 += v; sq2 += v*v;
        }
    }
    sm2 += __shfl_xor(sm2, 16, 64); sm2 += __shfl_xor(sm2, 32, 64);
    sq2 += __shfl_xor(sq2, 16, 64); sq2 += __shfl_xor(sq2, 32, 64);
    const float mean2 = sm2 * (1.f/128.f);
    const float rstd2 = rsqrtf(sq2 * (1.f/128.f) - mean2*mean2 + 1e-5f);

    // ---- epilogue: per col-half, bounce via Xs then coalesced gather+store ----
    #pragma unroll
    for (int ch = 0; ch < 2; ++ch) {
        #pragma unroll
        for (int mtL = 0; mtL < 4; ++mtL) {
            const int mt = ch*4 + mtL;
            const int col = mt*16 + G*4;
            f4v g2l = *(const f4v*)&g2v[col];
            f4v b2l = *(const f4v*)&b2v[col];
            float z0 = fmaxf((h2[mt][0]-mean2)*rstd2*g2l[0] + b2l[0], 0.f);
            float z1 = fmaxf((h2[mt][1]-mean2)*rstd2*g2l[1] + b2l[1], 0.f);
            float z2 = fmaxf((h2[mt][2]-mean2)*rstd2*g2l[2] + b2l[2], 0.f);
            float z3 = fmaxf((h2[mt][3]-mean2)*rstd2*g2l[3] + b2l[3], 0.f);
            uint2 p; p.x = packbf(z0, z1); p.y = packbf(z2, z3);
            int pg = (mtL*2 + (G >> 1)) ^ (rloc & 7);
            *(uint2*)(xs + rloc*128 + pg*16 + (G & 1)*8) = p;
        }
        asm volatile("s_waitcnt lgkmcnt(0)" ::: "memory");
        #pragma unroll
        for (int it = 0; it < 2; ++it) {
            const int g8  = lane & 7;
            const int rr  = it*8 + (lane >> 3);
            const int rl2 = wave*16 + rr;
            int pg = g8 ^ (rr & 7);
            s8v v = *(const s8v*)(xs + rl2*128 + pg*16);
            float y[8];
            #pragma unroll
            for (int e = 0; e < 8; ++e) y[e] = bf2f((unsigned short)v[e]);
            if (wrr[it] > 0) {
                #pragma unroll
                for (int e = 0; e < 8; ++e) y[e] += bf2f((unsigned short)gv[it][ch][e]);
            }
            float4 o0 = {y[0], y[1], y[2], y[3]};
            float4 o1 = {y[4], y[5], y[6], y[7]};
            float* op = out + (size_t)(row0 + rl2) * 128 + ch*64 + g8*8;
            *(float4*)op       = o0;
            *(float4*)(op + 4) = o1;
        }
        asm volatile("" ::: "memory");
    }
}

extern "C" void kernel_launch(void* const* d_in, const int* in_sizes, int n_in,
                              void* d_out, int out_size, void* d_ws, size_t ws_size,
                              hipStream_t stream)
{
    const float* fcoarse = (const float*)d_in[0];
    const float* ffine   = (const float*)d_in[1];
    const float* w1c = (const float*)d_in[2];
    const float* g1c = (const float*)d_in[3];
    const float* b1c = (const float*)d_in[4];
    const float* w2c = (const float*)d_in[5];
    const float* g2c = (const float*)d_in[6];
    const float* b2c = (const float*)d_in[7];
    const float* w1f = (const float*)d_in[8];
    const float* g1f = (const float*)d_in[9];
    const float* b1f = (const float*)d_in[10];
    const float* w2f = (const float*)d_in[11];
    const float* g2f = (const float*)d_in[12];
    const float* b2f = (const float*)d_in[13];
    const int* nrow  = (const int*)d_in[14];
    const int* ncol  = (const int*)d_in[15];

    float* out = (float*)d_out;
    const int Mf = 131072;

    // ws: fcB 8MB | winner 512KB | packs 160KB | folds 2KB | Xbf 33.5MB
    unsigned short* fcB = (unsigned short*)d_ws;
    char* base = (char*)d_ws;
    int*   winner = (int*)(base + 8u*1024*1024);
    short* p1c = (short*)(base + 8u*1024*1024 + 512u*1024);
    short* p2c = p1c + 256*128;
    short* p1f = p2c + 128*128;
    short* p2f = p1f + 128*128;
    float* s2c = (float*)(p2f + 128*128);
    float* bwc = s2c + 128;
    float* s2f = bwc + 128;
    float* bwf = s2f + 128;
    unsigned short* Xbf = (unsigned short*)(base + 9078784u);   // 33.5MB

    // dispatch 1: pack + folds + zero-winner + xcvt (no LDS, high occupancy)
    prep_mega<<<2218, 256, 0, stream>>>(w1c, w2c, g1c, b1c, w1f, w2f, g1f, b1f,
                                        p1c, p2c, p1f, p2f, s2c, bwc, s2f, bwf,
                                        winner, ffine, Xbf);

    // dispatch 2: coarse (256) + winner atomicMax (512)
    coarse_mega<<<768, 512, 0, stream>>>(
        fcoarse, p1c, p2c, s2c, bwc, g2c, b2c, fcB,
        nrow, ncol, winner);

    // dispatch 3: fine MLP + fused scatter -> out
    fine_mlp<<<Mf/128, 512, 0, stream>>>(
        Xbf, p1f, p2f, s2f, bwf, g2f, b2f,
        out, winner, fcB);
}